// Round 1
// baseline (104.419 us; speedup 1.0000x reference)
//
#include <hip/hip_runtime.h>

// Problem constants (from reference setup_inputs).
#define BATCH  4
#define NQ     8192
#define NA     6890
#define NSPLIT 16    // anchor splits = waves per block
#define QPB    64    // queries per block = one wave width
#define PER    432   // ceil(NA/NSPLIT) rounded to mult of 8
#define NPAIR  3445  // NA/2 anchor pairs per batch
#define PPW    216   // PER/2 pairs per wave (last wave: 205)

typedef float v2f __attribute__((ext_vector_type(2)));

// ---------------------------------------------------------------------------
// Prep: repack anchors [B][NA][3] (xyz interleaved) -> pair-SoA [B][NPAIR][6]
// layout (x0,x1, y0,y1, z0,z1) so each coord-pair is an adjacent, even-aligned
// SGPR pair usable directly as a v_pk_* 64-bit scalar operand.
// ---------------------------------------------------------------------------
__global__ void repack_kernel(const float* __restrict__ anchor,
                              float* __restrict__ packed) {
    const int t = blockIdx.x * blockDim.x + threadIdx.x;
    if (t >= BATCH * NPAIR) return;
    const int b = t / NPAIR, p = t - b * NPAIR;
    const float* s = anchor + ((size_t)b * NA + 2 * (size_t)p) * 3;
    float* d = packed + ((size_t)b * NPAIR + p) * 6;
    const v2f i0 = *(const v2f*)(s + 0);   // x0,y0
    const v2f i1 = *(const v2f*)(s + 2);   // z0,x1
    const v2f i2 = *(const v2f*)(s + 4);   // y1,z1
    ((v2f*)d)[0] = (v2f){i0.x, i1.y};      // x0,x1
    ((v2f*)d)[1] = (v2f){i0.y, i2.x};      // y0,y1
    ((v2f*)d)[2] = (v2f){i1.x, i2.y};      // z0,z1
}

// ---------------------------------------------------------------------------
// Packed-f32 main kernel: 2 anchors per v_pk_{add,mul,fma}_f32.
// 12 v2f (= 4 pairs = 8 anchors) per group, double-buffered in SGPRs.
// ---------------------------------------------------------------------------
#define DECL_PBUF(p) v2f p##0,p##1,p##2,p##3,p##4,p##5,p##6,p##7,p##8,p##9,p##10,p##11;
#define LOAD_PBUF(p, sp) do { const v2f* _s = (const v2f*)(sp); \
  p##0=_s[0]; p##1=_s[1]; p##2=_s[2];  p##3=_s[3];  p##4=_s[4];  p##5=_s[5]; \
  p##6=_s[6]; p##7=_s[7]; p##8=_s[8];  p##9=_s[9];  p##10=_s[10]; p##11=_s[11]; } while(0)

// Packed (d2,idx) key: d2>=0 so float bits order as uint; low 13 bits carry idx.
#define EVALP(ax,ay,az,idx) do { \
  const v2f _dx = qxx - (ax), _dy = qyy - (ay), _dz = qzz - (az); \
  const v2f _d  = __builtin_elementwise_fma(_dz,_dz, \
                    __builtin_elementwise_fma(_dy,_dy, _dx*_dx)); \
  const unsigned _kA = (__float_as_uint(_d.x) & 0xFFFFE000u) | (unsigned)(idx); \
  const unsigned _kB = (__float_as_uint(_d.y) & 0xFFFFE000u) | (unsigned)((idx)+1); \
  best0 = (_kA < best0) ? _kA : best0; \
  best1 = (_kB < best1) ? _kB : best1; } while(0)

#define COMP_PBUF(p, kk) do { \
  EVALP(p##0, p##1, p##2, (kk)+0); \
  EVALP(p##3, p##4, p##5, (kk)+2); \
  EVALP(p##6, p##7, p##8, (kk)+4); \
  EVALP(p##9, p##10,p##11,(kk)+6); } while(0)

__global__ __launch_bounds__(NSPLIT * 64)
void collision_pk_kernel(const float* __restrict__ query,
                         const float* __restrict__ packed,
                         const float* __restrict__ anchor,
                         const float* __restrict__ normals,
                         float* __restrict__ out) {
    __shared__ unsigned s_key[NSPLIT][QPB];

    const int lane = threadIdx.x & 63;
    const int wave = __builtin_amdgcn_readfirstlane((int)(threadIdx.x >> 6));
    const int blocksPerBatch = NQ / QPB;                  // 128
    const int b = blockIdx.x / blocksPerBatch;
    const int q = (blockIdx.x % blocksPerBatch) * QPB + lane;

    const float* qp = query + ((size_t)b * NQ + q) * 3;
    const float qx = qp[0], qy = qp[1], qz = qp[2];
    const v2f qxx = {qx, qx}, qyy = {qy, qy}, qzz = {qz, qz};

    // Contiguous anchor-pair range for this wave (uniform bounds).
    const int p0 = wave * PPW;
    const int p1 = (p0 + PPW < NPAIR) ? (p0 + PPW) : NPAIR;
    const int np = p1 - p0;                               // 216; last wave 205
    const int k0 = 2 * p0;                                // anchor index base
    const float* __restrict__ P = packed + (size_t)b * NPAIR * 6 + (size_t)p0 * 6;

    unsigned best0 = 0xFFFFFFFFu, best1 = 0xFFFFFFFFu;

    const int ng = np >> 2;         // groups of 4 pairs (8 anchors)
    DECL_PBUF(c) DECL_PBUF(t)
    if (ng >= 2) {
        LOAD_PBUF(c, P);
        int g = 0;
        while (g + 2 < ng) {
            LOAD_PBUF(t, P + 24 * (g + 1));
            COMP_PBUF(c, k0 + 8 * g);
            LOAD_PBUF(c, P + 24 * (g + 2));
            COMP_PBUF(t, k0 + 8 * (g + 1));
            g += 2;
        }
        if (g + 1 < ng) {
            LOAD_PBUF(t, P + 24 * (g + 1));
            COMP_PBUF(c, k0 + 8 * g);
            COMP_PBUF(t, k0 + 8 * (g + 1));
        } else {
            COMP_PBUF(c, k0 + 8 * g);
        }
    } else if (ng == 1) {
        LOAD_PBUF(c, P);
        COMP_PBUF(c, k0);
    }
    for (int pr = ng << 2; pr < np; ++pr) {   // pair tail (last wave: 1 pair)
        const v2f* s = (const v2f*)(P + 6 * pr);
        EVALP(s[0], s[1], s[2], k0 + 2 * pr);
    }

    s_key[wave][lane] = (best1 < best0) ? best1 : best0;
    __syncthreads();

    if (threadIdx.x < QPB) {
        unsigned bk = s_key[0][lane];
        #pragma unroll
        for (int s = 1; s < NSPLIT; ++s) {
            const unsigned v = s_key[s][lane];
            bk = (v < bk) ? v : bk;
        }
        const int bidx = (int)(bk & 8191u);
        const float* A = anchor + (size_t)b * NA * 3;
        const float* ap = A + (size_t)bidx * 3;
        const float* npnt = normals + ((size_t)b * NA + bidx) * 3;
        const float dx = qx - ap[0], dy = qy - ap[1], dz = qz - ap[2];
        const float d2  = fmaf(dz, dz, fmaf(dy, dy, dx * dx));
        const float dot = fmaf(dz, npnt[2], fmaf(dy, npnt[1], dx * npnt[0]));
        const bool coll = (dot < 0.0f) && (d2 <= 0.25f);
        const unsigned long long m = __ballot(coll);
        if (lane == 0) atomicAdd(out + b, (float)__popcll(m));
    }
}

// ---------------------------------------------------------------------------
// Fallback (verbatim previous kernel) if workspace is too small for repack.
// ---------------------------------------------------------------------------
#define DECL_BUF(p) \
  float p##00,p##01,p##02,p##03,p##04,p##05,p##06,p##07, \
        p##08,p##09,p##10,p##11,p##12,p##13,p##14,p##15, \
        p##16,p##17,p##18,p##19,p##20,p##21,p##22,p##23;

#define LOAD_BUF(p, sp) do { const float* _s = (sp); \
  p##00=_s[0];  p##01=_s[1];  p##02=_s[2];  p##03=_s[3]; \
  p##04=_s[4];  p##05=_s[5];  p##06=_s[6];  p##07=_s[7]; \
  p##08=_s[8];  p##09=_s[9];  p##10=_s[10]; p##11=_s[11]; \
  p##12=_s[12]; p##13=_s[13]; p##14=_s[14]; p##15=_s[15]; \
  p##16=_s[16]; p##17=_s[17]; p##18=_s[18]; p##19=_s[19]; \
  p##20=_s[20]; p##21=_s[21]; p##22=_s[22]; p##23=_s[23]; } while(0)

#define EVAL1(ax,ay,az,idx,acc) do { \
  const float _dx = qx-(ax), _dy = qy-(ay), _dz = qz-(az); \
  const float _d  = fmaf(_dz,_dz, fmaf(_dy,_dy, _dx*_dx)); \
  const unsigned _key = (__float_as_uint(_d) & 0xFFFFE000u) | (unsigned)(idx); \
  acc = (_key < acc) ? _key : acc; } while(0)

#define COMP_BUF(p, kk) do { \
  EVAL1(p##00,p##01,p##02,(kk)+0,best0); \
  EVAL1(p##03,p##04,p##05,(kk)+1,best1); \
  EVAL1(p##06,p##07,p##08,(kk)+2,best0); \
  EVAL1(p##09,p##10,p##11,(kk)+3,best1); \
  EVAL1(p##12,p##13,p##14,(kk)+4,best0); \
  EVAL1(p##15,p##16,p##17,(kk)+5,best1); \
  EVAL1(p##18,p##19,p##20,(kk)+6,best0); \
  EVAL1(p##21,p##22,p##23,(kk)+7,best1); } while(0)

__global__ __launch_bounds__(NSPLIT * 64)
void collision_kernel(const float* __restrict__ query,
                      const float* __restrict__ anchor,
                      const float* __restrict__ normals,
                      float* __restrict__ out) {
    __shared__ unsigned s_key[NSPLIT][QPB];

    const int lane = threadIdx.x & 63;
    const int wave = __builtin_amdgcn_readfirstlane((int)(threadIdx.x >> 6));
    const int blocksPerBatch = NQ / QPB;                  // 128
    const int b = blockIdx.x / blocksPerBatch;
    const int q = (blockIdx.x % blocksPerBatch) * QPB + lane;

    const float* qp = query + ((size_t)b * NQ + q) * 3;
    const float qx = qp[0], qy = qp[1], qz = qp[2];

    const float* __restrict__ A = anchor + (size_t)b * NA * 3;

    const int k0 = wave * PER;
    const int k1 = (k0 + PER < NA) ? (k0 + PER) : NA;
    const int n  = k1 - k0;
    const float* __restrict__ P = A + (size_t)3 * k0;

    unsigned best0 = 0xFFFFFFFFu, best1 = 0xFFFFFFFFu;

    const int ng = n >> 3;
    DECL_BUF(c) DECL_BUF(t)
    if (ng >= 2) {
        LOAD_BUF(c, P);
        int g = 0;
        while (g + 2 < ng) {
            LOAD_BUF(t, P + 24 * (g + 1));
            COMP_BUF(c, k0 + 8 * g);
            LOAD_BUF(c, P + 24 * (g + 2));
            COMP_BUF(t, k0 + 8 * (g + 1));
            g += 2;
        }
        if (g + 1 < ng) {
            LOAD_BUF(t, P + 24 * (g + 1));
            COMP_BUF(c, k0 + 8 * g);
            COMP_BUF(t, k0 + 8 * (g + 1));
        } else {
            COMP_BUF(c, k0 + 8 * g);
        }
    } else if (ng == 1) {
        LOAD_BUF(c, P);
        COMP_BUF(c, k0);
    }
    for (int k = ng << 3; k < n; ++k) {
        EVAL1(P[3*k+0], P[3*k+1], P[3*k+2], k0 + k, best0);
    }

    s_key[wave][lane] = (best1 < best0) ? best1 : best0;
    __syncthreads();

    if (threadIdx.x < QPB) {
        unsigned bk = s_key[0][lane];
        #pragma unroll
        for (int s = 1; s < NSPLIT; ++s) {
            const unsigned v = s_key[s][lane];
            bk = (v < bk) ? v : bk;
        }
        const int bidx = (int)(bk & 8191u);
        const float* ap = A + (size_t)bidx * 3;
        const float* npnt = normals + ((size_t)b * NA + bidx) * 3;
        const float dx = qx - ap[0], dy = qy - ap[1], dz = qz - ap[2];
        const float d2  = fmaf(dz, dz, fmaf(dy, dy, dx * dx));
        const float dot = fmaf(dz, npnt[2], fmaf(dy, npnt[1], dx * npnt[0]));
        const bool coll = (dot < 0.0f) && (d2 <= 0.25f);
        const unsigned long long m = __ballot(coll);
        if (lane == 0) atomicAdd(out + b, (float)__popcll(m));
    }
}

extern "C" void kernel_launch(void* const* d_in, const int* in_sizes, int n_in,
                              void* d_out, int out_size, void* d_ws, size_t ws_size,
                              hipStream_t stream) {
    const float* query   = (const float*)d_in[0];
    const float* anchor  = (const float*)d_in[1];
    const float* normals = (const float*)d_in[2];
    float* out = (float*)d_out;

    // d_out is poisoned with 0xAA before every call — zero it (graph-safe).
    hipMemsetAsync(d_out, 0, (size_t)out_size * sizeof(float), stream);

    const int grid = BATCH * (NQ / QPB);   // 512 blocks x 1024 threads
    const size_t WS_NEED = (size_t)BATCH * NPAIR * 6 * sizeof(float);  // ~331 KB

    if (d_ws && ws_size >= WS_NEED) {
        float* packed = (float*)d_ws;
        const int pthreads = BATCH * NPAIR;
        repack_kernel<<<dim3((pthreads + 255) / 256), dim3(256), 0, stream>>>(anchor, packed);
        collision_pk_kernel<<<dim3(grid), dim3(NSPLIT * 64), 0, stream>>>(
            query, packed, anchor, normals, out);
    } else {
        collision_kernel<<<dim3(grid), dim3(NSPLIT * 64), 0, stream>>>(
            query, anchor, normals, out);
    }
}